// Round 7
// baseline (511.203 us; speedup 1.0000x reference)
//
#include <hip/hip_runtime.h>
#include <hip/hip_bf16.h>

#define NN 32768
#define NE 524288
#define HID 128

typedef unsigned short u16;
typedef unsigned int u32;
typedef __bf16 bf16x8 __attribute__((ext_vector_type(8)));
typedef float f32x4 __attribute__((ext_vector_type(4)));

__device__ __forceinline__ u16 f2bf(float f) {
  return __builtin_bit_cast(u16, (__bf16)f);   // RNE via v_cvt
}
__device__ __forceinline__ float silu_f(float v) {
  return v * __builtin_amdgcn_rcpf(1.f + __expf(-v));
}
__device__ __forceinline__ bf16x8 cvt8(float4 a, float4 b) {
  bf16x8 r;
  r[0] = (__bf16)a.x; r[1] = (__bf16)a.y; r[2] = (__bf16)a.z; r[3] = (__bf16)a.w;
  r[4] = (__bf16)b.x; r[5] = (__bf16)b.y; r[6] = (__bf16)b.z; r[7] = (__bf16)b.w;
  return r;
}

// ---------------------------------------------------------------- prep ----
// x->bf16; w1/w2/wu1/wu2 -> bf16 col-major wT[col][k] (plain, no swizzle —
// B is consumed directly from global now). Fused recv-degree count.
__global__ __launch_bounds__(256) void prep_k(
    const float* __restrict__ x, const float* __restrict__ w1,
    const float* __restrict__ w2, const float* __restrict__ wu1,
    const float* __restrict__ wu2, const int* __restrict__ recv,
    u16* __restrict__ xb, u16* __restrict__ w1T, u16* __restrict__ w2T,
    u16* __restrict__ wu1T, u16* __restrict__ wu2T, int* __restrict__ cnt)
{
  int i = blockIdx.x * 256 + threadIdx.x;   // grid covers exactly NN*HID
  xb[i] = f2bf(x[i]);
  if (i < NE) atomicAdd(&cnt[recv[i]], 1);
  if (i < 3 * 128 * 128) {                  // w1T [s][c][k]
    int k = i & 127, c = (i >> 7) & 127, s = i >> 14;
    w1T[i] = f2bf(w1[(s * 128 + k) * 128 + c]);
  }
  if (i < 128 * 128) { int k = i & 127, c = i >> 7; w2T[i]  = f2bf(w2[k * 128 + c]); }
  if (i < 256 * 128) { int k = i & 127, c = i >> 7; wu1T[i] = f2bf(wu1[k * 256 + c]); }
  if (i < 128 * 256) { int k = i & 255, c = i >> 8; wu2T[i] = f2bf(wu2[k * 128 + c]); }
}

// exclusive scan of cnt[NN] -> off[NN+1]; cursor = copy of off
__global__ __launch_bounds__(1024) void scan_k(const int* __restrict__ cnt,
                                               int* __restrict__ off,
                                               int* __restrict__ cursor)
{
  __shared__ int part[1024];
  const int tid = threadIdx.x;
  const int base = tid * 32;
  int v[32];
  int s = 0;
  #pragma unroll
  for (int j = 0; j < 32; ++j) { v[j] = cnt[base + j]; s += v[j]; }
  part[tid] = s;
  __syncthreads();
  #pragma unroll 1
  for (int d = 1; d < 1024; d <<= 1) {
    int t = (tid >= d) ? part[tid - d] : 0;
    __syncthreads();
    part[tid] += t;
    __syncthreads();
  }
  int ex = part[tid] - s;
  #pragma unroll
  for (int j = 0; j < 32; ++j) {
    off[base + j] = ex;
    cursor[base + j] = ex;
    ex += v[j];
  }
  if (tid == 1023) off[NN] = ex;
}

__global__ __launch_bounds__(256) void scatter_k(const int* __restrict__ recv,
                                                 int* __restrict__ cursor,
                                                 int* __restrict__ eperm)
{
  int e = blockIdx.x * 256 + threadIdx.x;
  int r = recv[e];
  int pos = atomicAdd(&cursor[r], 1);
  eperm[pos] = e;
}

// ------------------------------------------------------------ edge MLP ----
// 64 CSR-ordered edges/block, 4 waves, wave tile 32 edges x 64 cols.
// ALL fragments direct global->register: A via per-lane node-row gathers
// (slice 0/1) or eattr f32+cvt (slice 2); B from L2-hot col-major weights.
// Whole-slice load batches (96 VGPR) -> compiler-pipelined; waves fully
// independent (only 3 block barriers: hidden exchange + reduce staging).
// LDS 16.6KB. Fused segmented scatter-mean epilogue. XCD-chunked swizzle.
__global__ __launch_bounds__(256, 3) void edge_mlp(
    const u16* __restrict__ xb, const float* __restrict__ eattr,
    const int* __restrict__ send, const int* __restrict__ recv,
    const int* __restrict__ eperm,
    const u16* __restrict__ w1T, const float* __restrict__ b1,
    const u16* __restrict__ w2T, const float* __restrict__ b2,
    float* __restrict__ msg_out, float* __restrict__ sums)
{
  __shared__ u16 sH[64 * 128];          // hidden / msg-bf16 (chunk-XOR swizzled)
  __shared__ int sNid[64];

  const int tid  = threadIdx.x;
  const int lane = tid & 63;
  const int w    = tid >> 6;            // 0..3
  const int wr   = w >> 1;              // 32-edge stripe
  const int wc   = w & 1;               // 64-col half
  const int fr   = lane & 15;
  const int fkq  = lane >> 4;
  const int orow = fkq * 4;
  // bijective XCD-chunked swizzle (gridDim.x = 8192, 8 XCDs)
  const int logical = ((int)blockIdx.x & 7) * ((int)gridDim.x >> 3)
                    + ((int)blockIdx.x >> 3);
  const int e0 = logical * 64;

  // per-lane edge/node ids for A-fragment rows (row0 = fr, row1 = 16+fr)
  const int eo0 = eperm[e0 + wr * 32 + fr];
  const int eo1 = eperm[e0 + wr * 32 + 16 + fr];
  const int ns0 = send[eo0], ns1 = send[eo1];
  const int nr0 = recv[eo0], nr1 = recv[eo1];
  if (wc == 0) { sNid[wr * 32 + fr] = nr0; sNid[wr * 32 + 16 + fr] = nr1; }

  float b1v[4], b2v[4];
  #pragma unroll
  for (int n = 0; n < 4; ++n) {
    b1v[n] = b1[wc * 64 + n * 16 + fr];
    b2v[n] = b2[wc * 64 + n * 16 + fr];
  }

  f32x4 acc[2][4];
  #pragma unroll
  for (int m = 0; m < 2; ++m)
    #pragma unroll
    for (int n = 0; n < 4; ++n)
      #pragma unroll
      for (int r = 0; r < 4; ++r) acc[m][n][r] = 0.f;

  bf16x8 aR[4][2], bR[4][4];

#define LOADB(WP)                                                          \
  _Pragma("unroll") for (int kk = 0; kk < 4; ++kk)                         \
    _Pragma("unroll") for (int n = 0; n < 4; ++n)                          \
      bR[kk][n] = *reinterpret_cast<const bf16x8*>((WP) + n * 2048 + kk * 32);

#define DOMFMA()                                                           \
  _Pragma("unroll") for (int kk = 0; kk < 4; ++kk) {                       \
    __builtin_amdgcn_s_setprio(1);                                         \
    _Pragma("unroll") for (int m = 0; m < 2; ++m)                          \
      _Pragma("unroll") for (int n = 0; n < 4; ++n)                        \
        acc[m][n] = __builtin_amdgcn_mfma_f32_16x16x32_bf16(               \
            aR[kk][m], bR[kk][n], acc[m][n], 0, 0, 0);                     \
    __builtin_amdgcn_s_setprio(0); }

  // ---- slice 0: x[send] @ W1a ----
  {
    const u16* a0 = xb + (size_t)ns0 * HID + fkq * 8;
    const u16* a1 = xb + (size_t)ns1 * HID + fkq * 8;
    #pragma unroll
    for (int kk = 0; kk < 4; ++kk) {
      aR[kk][0] = *reinterpret_cast<const bf16x8*>(a0 + kk * 32);
      aR[kk][1] = *reinterpret_cast<const bf16x8*>(a1 + kk * 32);
    }
    const u16* wp = w1T + (wc * 64 + fr) * HID + fkq * 8;
    LOADB(wp);
    DOMFMA();
  }
  // ---- slice 1: x[recv] @ W1b ----
  {
    const u16* a0 = xb + (size_t)nr0 * HID + fkq * 8;
    const u16* a1 = xb + (size_t)nr1 * HID + fkq * 8;
    #pragma unroll
    for (int kk = 0; kk < 4; ++kk) {
      aR[kk][0] = *reinterpret_cast<const bf16x8*>(a0 + kk * 32);
      aR[kk][1] = *reinterpret_cast<const bf16x8*>(a1 + kk * 32);
    }
    const u16* wp = w1T + 16384 + (wc * 64 + fr) * HID + fkq * 8;
    LOADB(wp);
    DOMFMA();
  }
  // ---- slice 2: eattr @ W1c (f32 load + cvt_pk) ----
  {
    const float* p0 = eattr + (size_t)eo0 * HID + fkq * 8;
    const float* p1 = eattr + (size_t)eo1 * HID + fkq * 8;
    #pragma unroll
    for (int kk = 0; kk < 4; ++kk) {
      float4 t0 = *reinterpret_cast<const float4*>(p0 + kk * 32);
      float4 t1 = *reinterpret_cast<const float4*>(p0 + kk * 32 + 4);
      float4 t2 = *reinterpret_cast<const float4*>(p1 + kk * 32);
      float4 t3 = *reinterpret_cast<const float4*>(p1 + kk * 32 + 4);
      aR[kk][0] = cvt8(t0, t1);
      aR[kk][1] = cvt8(t2, t3);
    }
    const u16* wp = w1T + 32768 + (wc * 64 + fr) * HID + fkq * 8;
    LOADB(wp);
    DOMFMA();
  }

  // hidden = silu(acc + b1) -> sH (swizzled), reset acc
  #pragma unroll
  for (int m = 0; m < 2; ++m)
    #pragma unroll
    for (int n = 0; n < 4; ++n) {
      int c = wc * 64 + n * 16 + fr;
      #pragma unroll
      for (int r = 0; r < 4; ++r) {
        int row = wr * 32 + m * 16 + orow + r;
        sH[(row << 7) + (((c >> 3) ^ (row & 7)) << 3) + (c & 7)] =
            f2bf(silu_f(acc[m][n][r] + b1v[n]));
        acc[m][n][r] = 0.f;
      }
    }
  __syncthreads();

  // ---- slice 3: hidden @ W2 (A from LDS, B direct) ----
  {
    #pragma unroll
    for (int kk = 0; kk < 4; ++kk)
      #pragma unroll
      for (int m = 0; m < 2; ++m) {
        int row = wr * 32 + m * 16 + fr;
        int ch = (kk * 4 + fkq) ^ (row & 7);
        aR[kk][m] = *reinterpret_cast<const bf16x8*>(sH + (row << 7) + (ch << 3));
      }
    const u16* wp = w2T + (wc * 64 + fr) * HID + fkq * 8;
    LOADB(wp);
    DOMFMA();
  }
#undef LOADB
#undef DOMFMA

  // edge ids for the C/D-layout rows
  int eg0[4], eg1[4];
  #pragma unroll
  for (int r = 0; r < 4; ++r) {
    eg0[r] = eperm[e0 + wr * 32 + orow + r];
    eg1[r] = eperm[e0 + wr * 32 + 16 + orow + r];
  }
  __syncthreads();                      // slice-3 sH reads done before overwrite

  // msg = silu(acc + b2) -> global (true edge id) + bf16 -> sH
  #pragma unroll
  for (int m = 0; m < 2; ++m)
    #pragma unroll
    for (int r = 0; r < 4; ++r) {
      int row = wr * 32 + m * 16 + orow + r;
      float* mp = msg_out + (size_t)(m ? eg1[r] : eg0[r]) * HID;
      #pragma unroll
      for (int n = 0; n < 4; ++n) {
        int c = wc * 64 + n * 16 + fr;
        float v = silu_f(acc[m][n][r] + b2v[n]);
        mp[c] = v;
        sH[(row << 7) + (((c >> 3) ^ (row & 7)) << 3) + (c & 7)] = f2bf(v);
      }
    }
  __syncthreads();

  // segmented column reduce: 2 groups x 32 rows, 128 cols
  {
    const int col = tid & 127, q = tid >> 7;
    float s = 0.f;
    int cur = sNid[q * 32];
    #pragma unroll 1
    for (int r = 0; r < 32; ++r) {
      int row = q * 32 + r;
      u16 hv = sH[(row << 7) + (((col >> 3) ^ (row & 7)) << 3) + (col & 7)];
      s += __builtin_bit_cast(float, (u32)hv << 16);
      int nxt = (r < 31) ? sNid[row + 1] : -1;
      if (nxt != cur) {
        atomicAdd(sums + (size_t)cur * HID + col, s);
        s = 0.f;
        cur = nxt;
      }
    }
  }
}

// ----------------------------------------------------------- node side ----
// xob = bf16(x + sums/max(cnt,1))
__global__ __launch_bounds__(256) void xin_k(
    const float* __restrict__ x, const float* __restrict__ sums,
    const int* __restrict__ cnt, u16* __restrict__ xob)
{
  int idx = blockIdx.x * 256 + threadIdx.x;   // NN*HID/4 float4s
  int node = idx >> 5;
  float inv = 1.f / fmaxf((float)cnt[node], 1.f);
  float4 xv = reinterpret_cast<const float4*>(x)[idx];
  float4 sv = reinterpret_cast<const float4*>(sums)[idx];
  float o0 = xv.x + sv.x * inv, o1 = xv.y + sv.y * inv;
  float o2 = xv.z + sv.z * inv, o3 = xv.w + sv.w * inv;
  uint2 wv;
  wv.x = (u32)f2bf(o0) | ((u32)f2bf(o1) << 16);
  wv.y = (u32)f2bf(o2) | ((u32)f2bf(o3) << 16);
  reinterpret_cast<uint2*>(xob)[idx] = wv;
}

// t = silu(xo_in @ wu1 + bu1)  [NN,256]
__global__ __launch_bounds__(256) void mlp1_k(
    const u16* __restrict__ xob, const u16* __restrict__ wu1T,
    const float* __restrict__ bu1, u16* __restrict__ t)
{
  __shared__ u16 sB[256][40];
  const int tid = threadIdx.x, lane = tid & 63, wid = tid >> 6;
  const int wr = wid >> 1, wc = wid & 1;
  const int fr = lane & 15, fk = (lane >> 4) * 8, orow = (lane >> 4) * 4;
  const int n0 = blockIdx.x * 64;

  f32x4 acc[2][8];
  #pragma unroll
  for (int m = 0; m < 2; ++m)
    #pragma unroll
    for (int n = 0; n < 8; ++n)
      #pragma unroll
      for (int r = 0; r < 4; ++r) acc[m][n][r] = 0.f;

  #pragma unroll 1
  for (int kk = 0; kk < 4; ++kk) {
    #pragma unroll
    for (int it = 0; it < 4; ++it) {
      int chunk = tid + it * 256;
      int c = chunk >> 2, q = chunk & 3;
      *reinterpret_cast<uint4*>(&sB[c][q * 8]) =
          *reinterpret_cast<const uint4*>(wu1T + c * 128 + kk * 32 + q * 8);
    }
    __syncthreads();
    bf16x8 aF[2], bF[8];
    #pragma unroll
    for (int m = 0; m < 2; ++m)
      aF[m] = __builtin_bit_cast(bf16x8, *reinterpret_cast<const uint4*>(
          xob + (size_t)(n0 + wr * 32 + m * 16 + fr) * HID + kk * 32 + fk));
    #pragma unroll
    for (int n = 0; n < 8; ++n)
      bF[n] = __builtin_bit_cast(bf16x8,
          *reinterpret_cast<const uint4*>(&sB[wc * 128 + n * 16 + fr][fk]));
    #pragma unroll
    for (int m = 0; m < 2; ++m)
      #pragma unroll
      for (int n = 0; n < 8; ++n)
        acc[m][n] = __builtin_amdgcn_mfma_f32_16x16x32_bf16(aF[m], bF[n], acc[m][n], 0, 0, 0);
    __syncthreads();
  }
  #pragma unroll
  for (int n = 0; n < 8; ++n) {
    int col = wc * 128 + n * 16 + fr;
    float bb = bu1[col];
    #pragma unroll
    for (int m = 0; m < 2; ++m) {
      int row = n0 + wr * 32 + m * 16 + orow;
      #pragma unroll
      for (int r = 0; r < 4; ++r)
        t[(size_t)(row + r) * 256 + col] = f2bf(silu_f(acc[m][n][r] + bb));
    }
  }
}

// xo = (x + sums/cnt) + t @ wu2 + bu2   (residual recomputed in f32)
__global__ __launch_bounds__(256) void mlp2_k(
    const u16* __restrict__ t, const u16* __restrict__ wu2T,
    const float* __restrict__ bu2, const float* __restrict__ x,
    const float* __restrict__ sums, const int* __restrict__ cnt,
    float* __restrict__ xo)
{
  __shared__ u16 sB[128][40];
  const int tid = threadIdx.x, lane = tid & 63, wid = tid >> 6;
  const int wr = wid >> 1, wc = wid & 1;
  const int fr = lane & 15, fk = (lane >> 4) * 8, orow = (lane >> 4) * 4;
  const int n0 = blockIdx.x * 64;

  f32x4 acc[2][4];
  #pragma unroll
  for (int m = 0; m < 2; ++m)
    #pragma unroll
    for (int n = 0; n < 4; ++n)
      #pragma unroll
      for (int r = 0; r < 4; ++r) acc[m][n][r] = 0.f;

  #pragma unroll 1
  for (int kk = 0; kk < 8; ++kk) {
    #pragma unroll
    for (int it = 0; it < 2; ++it) {
      int chunk = tid + it * 256;
      int c = chunk >> 2, q = chunk & 3;
      *reinterpret_cast<uint4*>(&sB[c][q * 8]) =
          *reinterpret_cast<const uint4*>(wu2T + c * 256 + kk * 32 + q * 8);
    }
    __syncthreads();
    bf16x8 aF[2], bF[4];
    #pragma unroll
    for (int m = 0; m < 2; ++m)
      aF[m] = __builtin_bit_cast(bf16x8, *reinterpret_cast<const uint4*>(
          t + (size_t)(n0 + wr * 32 + m * 16 + fr) * 256 + kk * 32 + fk));
    #pragma unroll
    for (int n = 0; n < 4; ++n)
      bF[n] = __builtin_bit_cast(bf16x8,
          *reinterpret_cast<const uint4*>(&sB[wc * 64 + n * 16 + fr][fk]));
    #pragma unroll
    for (int m = 0; m < 2; ++m)
      #pragma unroll
      for (int n = 0; n < 4; ++n)
        acc[m][n] = __builtin_amdgcn_mfma_f32_16x16x32_bf16(aF[m], bF[n], acc[m][n], 0, 0, 0);
    __syncthreads();
  }
  #pragma unroll
  for (int m = 0; m < 2; ++m) {
    #pragma unroll
    for (int r = 0; r < 4; ++r) {
      int gn = n0 + wr * 32 + m * 16 + orow + r;
      float inv = 1.f / fmaxf((float)cnt[gn], 1.f);
      #pragma unroll
      for (int n = 0; n < 4; ++n) {
        int col = wc * 64 + n * 16 + fr;
        float xi = x[(size_t)gn * HID + col] + sums[(size_t)gn * HID + col] * inv;
        xo[(size_t)gn * HID + col] = xi + acc[m][n][r] + bu2[col];
      }
    }
  }
}

// -------------------------------------------------------------- launch ----
extern "C" void kernel_launch(void* const* d_in, const int* in_sizes, int n_in,
                              void* d_out, int out_size, void* d_ws, size_t ws_size,
                              hipStream_t stream)
{
  (void)in_sizes; (void)n_in; (void)out_size; (void)ws_size;
  const float* x     = (const float*)d_in[0];
  const float* eattr = (const float*)d_in[1];
  const int*   edges = (const int*)d_in[2];
  const float* w1  = (const float*)d_in[3];
  const float* b1  = (const float*)d_in[4];
  const float* w2  = (const float*)d_in[5];
  const float* b2  = (const float*)d_in[6];
  const float* wu1 = (const float*)d_in[7];
  const float* bu1 = (const float*)d_in[8];
  const float* wu2 = (const float*)d_in[9];
  const float* bu2 = (const float*)d_in[10];

  float* xo  = (float*)d_out;
  float* msg = xo + (size_t)NN * HID;

  char* p = (char*)d_ws;                       // ~53 MB total
  u16* xb    = (u16*)p; p += (size_t)NN * HID * 2;
  u16* w1T   = (u16*)p; p += 384 * 128 * 2;
  u16* w2T   = (u16*)p; p += 128 * 128 * 2;
  u16* wu1T  = (u16*)p; p += 256 * 128 * 2;
  u16* wu2T  = (u16*)p; p += 128 * 256 * 2;
  u16* xob   = (u16*)p; p += (size_t)NN * HID * 2;
  u16* tbuf  = (u16*)p; p += (size_t)NN * 256 * 2;
  float* sums = (float*)p; p += (size_t)NN * HID * 4;
  int* cnt    = (int*)p; p += (size_t)NN * 4;
  int* off    = (int*)p; p += (size_t)(NN + 64) * 4;
  int* cursor = (int*)p; p += (size_t)NN * 4;
  int* eperm  = (int*)p; p += (size_t)NE * 4;

  const int* send = edges;
  const int* recv = edges + NE;

  hipMemsetAsync(cnt, 0, (size_t)NN * 4, stream);
  hipMemsetAsync(sums, 0, (size_t)NN * HID * 4, stream);
  prep_k<<<NN * HID / 256, 256, 0, stream>>>(x, w1, w2, wu1, wu2, recv,
                                             xb, w1T, w2T, wu1T, wu2T, cnt);
  scan_k<<<1, 1024, 0, stream>>>(cnt, off, cursor);
  scatter_k<<<NE / 256, 256, 0, stream>>>(recv, cursor, eperm);
  edge_mlp<<<NE / 64, 256, 0, stream>>>(xb, eattr, send, recv, eperm,
                                        w1T, b1, w2T, b2, msg, sums);
  xin_k<<<NN * HID / 4 / 256, 256, 0, stream>>>(x, sums, cnt, xob);
  mlp1_k<<<NN / 64, 256, 0, stream>>>(xob, wu1T, bu1, tbuf);
  mlp2_k<<<NN / 64, 256, 0, stream>>>(tbuf, wu2T, bu2, x, sums, cnt, xo);
}

// Round 8
// 324.513 us; speedup vs baseline: 1.5753x; 1.5753x over previous
//
#include <hip/hip_runtime.h>
#include <hip/hip_bf16.h>

#define NN 32768
#define NE 524288
#define HID 128

typedef unsigned short u16;
typedef unsigned int u32;
typedef __bf16 bf16x8 __attribute__((ext_vector_type(8)));
typedef float f32x4 __attribute__((ext_vector_type(4)));

__device__ __forceinline__ u16 f2bf(float f) {
  return __builtin_bit_cast(u16, (__bf16)f);   // RNE via v_cvt
}
__device__ __forceinline__ float silu_f(float v) {
  return v * __builtin_amdgcn_rcpf(1.f + __expf(-v));
}
__device__ __forceinline__ bf16x8 cvt8(float4 a, float4 b) {
  bf16x8 r;
  r[0] = (__bf16)a.x; r[1] = (__bf16)a.y; r[2] = (__bf16)a.z; r[3] = (__bf16)a.w;
  r[4] = (__bf16)b.x; r[5] = (__bf16)b.y; r[6] = (__bf16)b.z; r[7] = (__bf16)b.w;
  return r;
}
__device__ __forceinline__ float4 f4fma(float4 x, float4 s, float inv) {
  return make_float4(x.x + s.x * inv, x.y + s.y * inv,
                     x.z + s.z * inv, x.w + s.w * inv);
}

// async global->LDS, 16B/lane; LDS dest = wave-uniform base + lane*16
__device__ __forceinline__ void gld16(const void* g, void* l) {
  __builtin_amdgcn_global_load_lds(
      (const __attribute__((address_space(1))) u32*)g,
      (__attribute__((address_space(3))) u32*)l, 16, 0, 0);
}

#define WV(N)  do { asm volatile("s_waitcnt vmcnt(" #N ")" ::: "memory"); \
                    __builtin_amdgcn_sched_barrier(0); } while (0)
#define WVL(N) do { asm volatile("s_waitcnt vmcnt(" #N ") lgkmcnt(0)" ::: "memory"); \
                    __builtin_amdgcn_sched_barrier(0); } while (0)
#define WL()   do { asm volatile("s_waitcnt lgkmcnt(0)" ::: "memory"); \
                    __builtin_amdgcn_sched_barrier(0); } while (0)
__device__ __forceinline__ void bar() {
  __builtin_amdgcn_sched_barrier(0);
  __builtin_amdgcn_s_barrier();
  __builtin_amdgcn_sched_barrier(0);
}

// ---------------------------------------------------------------- prep ----
// x->bf16; w1/w2 -> col-major + 16B-chunk XOR pre-swizzle (for gld16);
// wu1/wu2 plain col-major; fused recv-degree count (cnt pre-zeroed).
__global__ __launch_bounds__(256) void prep_k(
    const float* __restrict__ x, const float* __restrict__ w1,
    const float* __restrict__ w2, const float* __restrict__ wu1,
    const float* __restrict__ wu2, const int* __restrict__ recv,
    u16* __restrict__ xb, u16* __restrict__ w1Ts, u16* __restrict__ w2Ts,
    u16* __restrict__ wu1T, u16* __restrict__ wu2T, int* __restrict__ cnt)
{
  int i = blockIdx.x * 256 + threadIdx.x;   // grid covers exactly NN*HID
  xb[i] = f2bf(x[i]);
  if (i < NE) atomicAdd(&cnt[recv[i]], 1);
  if (i < 3 * 128 * 128) {                  // w1Ts [s][c][q^(c&7)][j]
    int j = i & 7, qs = (i >> 3) & 15, c = (i >> 7) & 127, s = i >> 14;
    int k = s * 128 + ((qs ^ (c & 7)) << 3) + j;
    w1Ts[i] = f2bf(w1[k * 128 + c]);
  }
  if (i < 128 * 128) {                      // w2Ts [c][q^(c&7)][j]
    int j = i & 7, qs = (i >> 3) & 15, c = i >> 7;
    int k = ((qs ^ (c & 7)) << 3) + j;
    w2Ts[i] = f2bf(w2[k * 128 + c]);
  }
  if (i < 256 * 128) { int c = i >> 7, k = i & 127; wu1T[i] = f2bf(wu1[k * 256 + c]); }
  if (i < 128 * 256) { int c = i >> 8, k = i & 255; wu2T[i] = f2bf(wu2[k * 128 + c]); }
}

// exclusive scan of cnt[NN] -> cursor
__global__ __launch_bounds__(1024) void scan_k(const int* __restrict__ cnt,
                                               int* __restrict__ cursor)
{
  __shared__ int part[1024];
  const int tid = threadIdx.x;
  const int base = tid * 32;
  int v[32];
  int s = 0;
  #pragma unroll
  for (int j = 0; j < 32; ++j) { v[j] = cnt[base + j]; s += v[j]; }
  part[tid] = s;
  __syncthreads();
  #pragma unroll 1
  for (int d = 1; d < 1024; d <<= 1) {
    int t = (tid >= d) ? part[tid - d] : 0;
    __syncthreads();
    part[tid] += t;
    __syncthreads();
  }
  int ex = part[tid] - s;
  #pragma unroll
  for (int j = 0; j < 32; ++j) {
    cursor[base + j] = ex;
    ex += v[j];
  }
}

__global__ __launch_bounds__(256) void scatter_k(const int* __restrict__ recv,
                                                 int* __restrict__ cursor,
                                                 int* __restrict__ eperm)
{
  int e = blockIdx.x * 256 + threadIdx.x;
  int r = recv[e];
  int pos = atomicAdd(&cursor[r], 1);
  eperm[pos] = e;
}

// ------------------------------------------------------------ edge MLP ----
// R3's proven core (128 CSR-ordered edges/block, 8 waves, wave tile 32x64,
// full shared sA/sB panels staged via gld16, fat 32-MFMA phases, 2 blk/CU)
// + T14 eattr register prefetch at prologue (rides under slice-0 compute)
// + fused segmented scatter-mean epilogue + XCD-chunked tile mapping.
__global__ __launch_bounds__(512, 4) void edge_mlp(
    const u16* __restrict__ xb, const float* __restrict__ eattr,
    const int* __restrict__ send, const int* __restrict__ recv,
    const int* __restrict__ eperm,
    const u16* __restrict__ w1Ts, const float* __restrict__ b1,
    const u16* __restrict__ w2Ts, const float* __restrict__ b2,
    float* __restrict__ msg_out, float* __restrict__ sums)
{
  __shared__ u16 sA[128 * 128];
  __shared__ u16 sB[128 * 128];
  __shared__ int sNid[128];

  const int tid  = threadIdx.x;
  const int lane = tid & 63;
  const int w    = tid >> 6;
  const int wr   = w >> 1;              // 0..3: 32-edge stripe
  const int wc   = w & 1;               // 0..1: 64-col half
  const int fr   = lane & 15;
  const int fkq  = lane >> 4;
  const int orow = fkq * 4;
  const int lrow4 = lane >> 4;
  const int schk  = lane & 15;
  // bijective XCD-chunked tile mapping (gridDim = 4096, 4096 % 8 == 0)
  const int logical = ((int)blockIdx.x & 7) * ((int)gridDim.x >> 3)
                    + ((int)blockIdx.x >> 3);
  const int e0 = logical * 128;

  // ---- prologue: ids for this wave's 16 staging rows ----
  int eo[4], ns[4], nr[4], rl[4];
  #pragma unroll
  for (int i = 0; i < 4; ++i) {
    rl[i] = w * 16 + i * 4 + lrow4;
    eo[i] = eperm[e0 + rl[i]];
  }
  #pragma unroll
  for (int i = 0; i < 4; ++i) {
    ns[i] = send[eo[i]];
    nr[i] = recv[eo[i]];
    if (schk == 0) sNid[rl[i]] = nr[i];
  }

  f32x4 acc[2][4];
  #pragma unroll
  for (int m = 0; m < 2; ++m)
    #pragma unroll
    for (int n = 0; n < 4; ++n)
      #pragma unroll
      for (int r = 0; r < 4; ++r) acc[m][n][r] = 0.f;

  // issue s0 staging (8 glds), THEN eattr prefetch (8 float4, rides)
  #pragma unroll
  for (int i = 0; i < 4; ++i)
    gld16(xb + ((size_t)ns[i] << 7) + ((schk ^ (rl[i] & 7)) << 3),
          sA + ((w * 16 + i * 4) << 7));
  #pragma unroll
  for (int i = 0; i < 4; ++i)
    gld16(w1Ts + ((w * 16 + i * 4) << 7) + (lane << 3),
          sB + ((w * 16 + i * 4) << 7));
  __builtin_amdgcn_sched_barrier(0);
  float4 ea0[4], ea1[4];
  #pragma unroll
  for (int i = 0; i < 4; ++i) {
    const float* ep = eattr + ((size_t)eo[i] << 7) + ((schk ^ (rl[i] & 7)) << 3);
    ea0[i] = *reinterpret_cast<const float4*>(ep);
    ea1[i] = *reinterpret_cast<const float4*>(ep + 4);
  }
  __builtin_amdgcn_sched_barrier(0);

  // one slice pass: 4 kk x (2 aF + 4 bF swizzled reads, 8 MFMAs)
  auto cslice = [&](const u16* bufA) {
    #pragma unroll
    for (int kk = 0; kk < 4; ++kk) {
      bf16x8 aF[2], bF[4];
      #pragma unroll
      for (int m = 0; m < 2; ++m) {
        int row = wr * 32 + m * 16 + fr;
        int ch = (kk * 4 + fkq) ^ (row & 7);
        aF[m] = __builtin_bit_cast(bf16x8,
            *reinterpret_cast<const uint4*>(bufA + (row << 7) + (ch << 3)));
      }
      #pragma unroll
      for (int n = 0; n < 4; ++n) {
        int c = wc * 64 + n * 16 + fr;
        int ch = (kk * 4 + fkq) ^ (c & 7);
        bF[n] = __builtin_bit_cast(bf16x8,
            *reinterpret_cast<const uint4*>(sB + (c << 7) + (ch << 3)));
      }
      __builtin_amdgcn_s_setprio(1);
      #pragma unroll
      for (int m = 0; m < 2; ++m)
        #pragma unroll
        for (int n = 0; n < 4; ++n)
          acc[m][n] = __builtin_amdgcn_mfma_f32_16x16x32_bf16(aF[m], bF[n], acc[m][n], 0, 0, 0);
      __builtin_amdgcn_s_setprio(0);
    }
  };

  WV(8); bar();                         // s0 glds landed; eattr rides
  // bias loads (L2, hidden under slice-0 compute)
  float b1v[4], b2v[4];
  #pragma unroll
  for (int n = 0; n < 4; ++n) {
    b1v[n] = b1[wc * 64 + n * 16 + fr];
    b2v[n] = b2[wc * 64 + n * 16 + fr];
  }
  cslice(sA);                           // slice 0: x[send] @ W1a
  bar();
  // stage s1
  #pragma unroll
  for (int i = 0; i < 4; ++i)
    gld16(xb + ((size_t)nr[i] << 7) + ((schk ^ (rl[i] & 7)) << 3),
          sA + ((w * 16 + i * 4) << 7));
  #pragma unroll
  for (int i = 0; i < 4; ++i)
    gld16(w1Ts + 16384 + ((w * 16 + i * 4) << 7) + (lane << 3),
          sB + ((w * 16 + i * 4) << 7));
  WV(0); bar();                         // eattr long retired; s1 landed
  cslice(sA);                           // slice 1: x[recv] @ W1b
  bar();
  // stage s2: eattr regs -> sA (cvt8 + ds_write_b128), W1c -> sB
  #pragma unroll
  for (int i = 0; i < 4; ++i)
    *reinterpret_cast<uint4*>(sA + (rl[i] << 7) + (schk << 3)) =
        __builtin_bit_cast(uint4, cvt8(ea0[i], ea1[i]));
  #pragma unroll
  for (int i = 0; i < 4; ++i)
    gld16(w1Ts + 32768 + ((w * 16 + i * 4) << 7) + (lane << 3),
          sB + ((w * 16 + i * 4) << 7));
  WVL(0); bar();
  cslice(sA);                           // slice 2: eattr @ W1c
  bar();
  // hidden = silu(acc + b1) -> sA (swizzled b16), stage W2 -> sB, reset acc
  #pragma unroll
  for (int i = 0; i < 4; ++i)
    gld16(w2Ts + ((w * 16 + i * 4) << 7) + (lane << 3),
          sB + ((w * 16 + i * 4) << 7));
  #pragma unroll
  for (int n = 0; n < 4; ++n) {
    int c = wc * 64 + n * 16 + fr;
    #pragma unroll
    for (int m = 0; m < 2; ++m)
      #pragma unroll
      for (int r = 0; r < 4; ++r) {
        int row = wr * 32 + m * 16 + orow + r;
        sA[(row << 7) + (((c >> 3) ^ (row & 7)) << 3) + (c & 7)] =
            f2bf(silu_f(acc[m][n][r] + b1v[n]));
        acc[m][n][r] = 0.f;
      }
  }
  WVL(0); bar();
  cslice(sA);                           // slice 3: hidden @ W2

  // epilogue edge ids (C/D rows)
  int eg0[4], eg1[4];
  #pragma unroll
  for (int r = 0; r < 4; ++r) {
    eg0[r] = eperm[e0 + wr * 32 + orow + r];
    eg1[r] = eperm[e0 + wr * 32 + 16 + orow + r];
  }
  bar();                                // all sA reads (slice 3) done

  // msg = silu(acc + b2) -> global f32 + bf16 -> sA for the reduce
  #pragma unroll
  for (int m = 0; m < 2; ++m)
    #pragma unroll
    for (int r = 0; r < 4; ++r) {
      int row = wr * 32 + m * 16 + orow + r;
      float* mp = msg_out + ((size_t)(m ? eg1[r] : eg0[r]) << 7);
      #pragma unroll
      for (int n = 0; n < 4; ++n) {
        int c = wc * 64 + n * 16 + fr;
        float v = silu_f(acc[m][n][r] + b2v[n]);
        mp[c] = v;
        sA[(row << 7) + (((c >> 3) ^ (row & 7)) << 3) + (c & 7)] = f2bf(v);
      }
    }
  WL(); bar();

  // segmented column reduce: 4 groups x 32 rows, 128 cols
  {
    const int col = tid & 127, q = tid >> 7;
    float s = 0.f;
    int cur = sNid[q * 32];
    #pragma unroll 1
    for (int r = 0; r < 32; ++r) {
      int row = q * 32 + r;
      u16 hv = sA[(row << 7) + (((col >> 3) ^ (row & 7)) << 3) + (col & 7)];
      s += __builtin_bit_cast(float, (u32)hv << 16);
      int nxt = (r < 31) ? sNid[row + 1] : -1;
      if (nxt != cur) {
        atomicAdd(sums + (size_t)cur * HID + col, s);
        s = 0.f;
        cur = nxt;
      }
    }
  }
}

// ----------------------------------------------------------- update MLP ----
// t = silu((x + sums/cnt) @ wu1 + bu1)  [NN,256] — xin fused into A-fragments
__global__ __launch_bounds__(256) void mlp1_k(
    const float* __restrict__ x, const float* __restrict__ sums,
    const int* __restrict__ cnt, const u16* __restrict__ wu1T,
    const float* __restrict__ bu1, u16* __restrict__ t)
{
  __shared__ u16 sB[256][40];
  const int tid = threadIdx.x, lane = tid & 63, wid = tid >> 6;
  const int wr = wid >> 1, wc = wid & 1;
  const int fr = lane & 15, fkq = lane >> 4, fk = fkq * 8, orow = fkq * 4;
  const int n0 = blockIdx.x * 64;

  float invm[2];
  #pragma unroll
  for (int m = 0; m < 2; ++m)
    invm[m] = __builtin_amdgcn_rcpf(fmaxf((float)cnt[n0 + wr * 32 + m * 16 + fr], 1.f));

  f32x4 acc[2][8];
  #pragma unroll
  for (int m = 0; m < 2; ++m)
    #pragma unroll
    for (int n = 0; n < 8; ++n)
      #pragma unroll
      for (int r = 0; r < 4; ++r) acc[m][n][r] = 0.f;

  #pragma unroll 1
  for (int kk = 0; kk < 4; ++kk) {
    #pragma unroll
    for (int it = 0; it < 4; ++it) {
      int chunk = tid + it * 256;
      int c = chunk >> 2, q = chunk & 3;
      *reinterpret_cast<uint4*>(&sB[c][q * 8]) =
          *reinterpret_cast<const uint4*>(wu1T + c * 128 + kk * 32 + q * 8);
    }
    __syncthreads();
    bf16x8 aF[2], bF[8];
    #pragma unroll
    for (int m = 0; m < 2; ++m) {
      size_t base = (size_t)(n0 + wr * 32 + m * 16 + fr) * HID + kk * 32 + fk;
      float4 xv0 = *reinterpret_cast<const float4*>(x + base);
      float4 xv1 = *reinterpret_cast<const float4*>(x + base + 4);
      float4 sv0 = *reinterpret_cast<const float4*>(sums + base);
      float4 sv1 = *reinterpret_cast<const float4*>(sums + base + 4);
      aF[m] = cvt8(f4fma(xv0, sv0, invm[m]), f4fma(xv1, sv1, invm[m]));
    }
    #pragma unroll
    for (int n = 0; n < 8; ++n)
      bF[n] = __builtin_bit_cast(bf16x8,
          *reinterpret_cast<const uint4*>(&sB[wc * 128 + n * 16 + fr][fk]));
    #pragma unroll
    for (int m = 0; m < 2; ++m)
      #pragma unroll
      for (int n = 0; n < 8; ++n)
        acc[m][n] = __builtin_amdgcn_mfma_f32_16x16x32_bf16(aF[m], bF[n], acc[m][n], 0, 0, 0);
    __syncthreads();
  }
  #pragma unroll
  for (int n = 0; n < 8; ++n) {
    int col = wc * 128 + n * 16 + fr;
    float bb = bu1[col];
    #pragma unroll
    for (int m = 0; m < 2; ++m) {
      int row = n0 + wr * 32 + m * 16 + orow;
      #pragma unroll
      for (int r = 0; r < 4; ++r)
        t[(size_t)(row + r) * 256 + col] = f2bf(silu_f(acc[m][n][r] + bb));
    }
  }
}

// xo = (x + sums/cnt) + t @ wu2 + bu2   (residual recomputed in f32)
__global__ __launch_bounds__(256) void mlp2_k(
    const u16* __restrict__ t, const u16* __restrict__ wu2T,
    const float* __restrict__ bu2, const float* __restrict__ x,
    const float* __restrict__ sums, const int* __restrict__ cnt,
    float* __restrict__ xo)
{
  __shared__ u16 sB[128][40];
  const int tid = threadIdx.x, lane = tid & 63, wid = tid >> 6;
  const int wr = wid >> 1, wc = wid & 1;
  const int fr = lane & 15, fk = (lane >> 4) * 8, orow = (lane >> 4) * 4;
  const int n0 = blockIdx.x * 64;

  f32x4 acc[2][4];
  #pragma unroll
  for (int m = 0; m < 2; ++m)
    #pragma unroll
    for (int n = 0; n < 4; ++n)
      #pragma unroll
      for (int r = 0; r < 4; ++r) acc[m][n][r] = 0.f;

  #pragma unroll 1
  for (int kk = 0; kk < 8; ++kk) {
    #pragma unroll
    for (int it = 0; it < 2; ++it) {
      int chunk = tid + it * 256;
      int c = chunk >> 2, q = chunk & 3;
      *reinterpret_cast<uint4*>(&sB[c][q * 8]) =
          *reinterpret_cast<const uint4*>(wu2T + c * 256 + kk * 32 + q * 8);
    }
    __syncthreads();
    bf16x8 aF[2], bF[4];
    #pragma unroll
    for (int m = 0; m < 2; ++m)
      aF[m] = __builtin_bit_cast(bf16x8, *reinterpret_cast<const uint4*>(
          t + (size_t)(n0 + wr * 32 + m * 16 + fr) * 256 + kk * 32 + fk));
    #pragma unroll
    for (int n = 0; n < 4; ++n)
      bF[n] = __builtin_bit_cast(bf16x8,
          *reinterpret_cast<const uint4*>(&sB[wc * 64 + n * 16 + fr][fk]));
    #pragma unroll
    for (int m = 0; m < 2; ++m)
      #pragma unroll
      for (int n = 0; n < 4; ++n)
        acc[m][n] = __builtin_amdgcn_mfma_f32_16x16x32_bf16(aF[m], bF[n], acc[m][n], 0, 0, 0);
    __syncthreads();
  }
  #pragma unroll
  for (int m = 0; m < 2; ++m) {
    #pragma unroll
    for (int r = 0; r < 4; ++r) {
      int gn = n0 + wr * 32 + m * 16 + orow + r;
      float inv = 1.f / fmaxf((float)cnt[gn], 1.f);
      #pragma unroll
      for (int n = 0; n < 4; ++n) {
        int col = wc * 64 + n * 16 + fr;
        float xi = x[(size_t)gn * HID + col] + sums[(size_t)gn * HID + col] * inv;
        xo[(size_t)gn * HID + col] = xi + acc[m][n][r] + bu2[col];
      }
    }
  }
}

// -------------------------------------------------------------- launch ----
extern "C" void kernel_launch(void* const* d_in, const int* in_sizes, int n_in,
                              void* d_out, int out_size, void* d_ws, size_t ws_size,
                              hipStream_t stream)
{
  (void)in_sizes; (void)n_in; (void)out_size; (void)ws_size;
  const float* x     = (const float*)d_in[0];
  const float* eattr = (const float*)d_in[1];
  const int*   edges = (const int*)d_in[2];
  const float* w1  = (const float*)d_in[3];
  const float* b1  = (const float*)d_in[4];
  const float* w2  = (const float*)d_in[5];
  const float* b2  = (const float*)d_in[6];
  const float* wu1 = (const float*)d_in[7];
  const float* bu1 = (const float*)d_in[8];
  const float* wu2 = (const float*)d_in[9];
  const float* bu2 = (const float*)d_in[10];

  float* xo  = (float*)d_out;
  float* msg = xo + (size_t)NN * HID;

  char* p = (char*)d_ws;                       // ~45 MB total
  u16* xb    = (u16*)p; p += (size_t)NN * HID * 2;
  u16* w1Ts  = (u16*)p; p += 384 * 128 * 2;
  u16* w2Ts  = (u16*)p; p += 128 * 128 * 2;
  u16* wu1T  = (u16*)p; p += 256 * 128 * 2;
  u16* wu2T  = (u16*)p; p += 128 * 256 * 2;
  u16* tbuf  = (u16*)p; p += (size_t)NN * 256 * 2;
  float* sums = (float*)p; p += (size_t)NN * HID * 4;
  int* cnt    = (int*)p; p += (size_t)NN * 4;
  int* cursor = (int*)p; p += (size_t)NN * 4;
  int* eperm  = (int*)p; p += (size_t)NE * 4;

  const int* send = edges;
  const int* recv = edges + NE;

  hipMemsetAsync(cnt, 0, (size_t)NN * 4, stream);
  hipMemsetAsync(sums, 0, (size_t)NN * HID * 4, stream);
  prep_k<<<NN * HID / 256, 256, 0, stream>>>(x, w1, w2, wu1, wu2, recv,
                                             xb, w1Ts, w2Ts, wu1T, wu2T, cnt);
  scan_k<<<1, 1024, 0, stream>>>(cnt, cursor);
  scatter_k<<<NE / 256, 256, 0, stream>>>(recv, cursor, eperm);
  edge_mlp<<<NE / 128, 512, 0, stream>>>(xb, eattr, send, recv, eperm,
                                         w1Ts, b1, w2Ts, b2, msg, sums);
  mlp1_k<<<NN / 64, 256, 0, stream>>>(x, sums, cnt, wu1T, bu1, tbuf);
  mlp2_k<<<NN / 64, 256, 0, stream>>>(tbuf, wu2T, bu2, x, sums, cnt, xo);
}